// Round 12
// baseline (142.235 us; speedup 1.0000x reference)
//
#include <hip/hip_runtime.h>
#include <math.h>

#define T_SEQ 2048
#define E 768
#define WIN 1024
#define KDIM 768
#define HS_SZ ((size_t)4096 * 768)
#define SCALE 0.21650635094610965f

typedef _Float16 f16x8 __attribute__((ext_vector_type(8)));
typedef _Float16 f16x4 __attribute__((ext_vector_type(4)));
typedef float f32x4 __attribute__((ext_vector_type(4)));
typedef __attribute__((address_space(3))) _Float16 lf16;

#define MFMA16(a, b, c) __builtin_amdgcn_mfma_f32_16x16x32_f16(a, b, c, 0, 0, 0)

__device__ __forceinline__ void dma16(const _Float16* g, lf16* l) {
    __builtin_amdgcn_global_load_lds(
        (const __attribute__((address_space(1))) void*)g,
        (__attribute__((address_space(3))) void*)l, 16, 0, 0);
}

// ---------------- prep: f16 casts + rotary table ----------------
__device__ __forceinline__ void cast8(const float* __restrict__ src,
                                      _Float16* __restrict__ dst, int i) {
    float4 a = *(const float4*)&src[i];
    float4 b = *(const float4*)&src[i + 4];
    f16x8 h;
    h[0] = (_Float16)a.x; h[1] = (_Float16)a.y; h[2] = (_Float16)a.z; h[3] = (_Float16)a.w;
    h[4] = (_Float16)b.x; h[5] = (_Float16)b.y; h[6] = (_Float16)b.z; h[7] = (_Float16)b.w;
    *(f16x8*)&dst[i] = h;
}

__global__ __launch_bounds__(256) void prep(
    const float* __restrict__ hs,
    const float* __restrict__ Wq, const float* __restrict__ Wk,
    const float* __restrict__ Wv, const float* __restrict__ Wo,
    _Float16* __restrict__ hs16,
    _Float16* __restrict__ Wq16, _Float16* __restrict__ Wk16,
    _Float16* __restrict__ Wv16, _Float16* __restrict__ Wo16,
    float2* __restrict__ rtab) {
    int tid = blockIdx.x * 256 + threadIdx.x;
    int i = tid * 8;
    if (i < 768 * 768) { cast8(Wq, Wq16, i); cast8(Wo, Wo16, i); }
    if (i < 192 * 768) { cast8(Wk, Wk16, i); cast8(Wv, Wv16, i); }
    cast8(hs, hs16, i);
    if (tid < 2048 * 32) {
        int t = tid >> 5, d = tid & 31;
        float inv = powf(10000.0f, -(float)(2 * d) * (1.0f / 64.0f));
        float s, c;
        sincosf((float)t * inv, &s, &c);
        rtab[tid] = make_float2(c, s);
    }
}

// ---------------- QKV GEMM: pure f16, 128x64, BK=128, DMA + XOR swizzle -----
__global__ __launch_bounds__(256) void gemm_qkv(
    const _Float16* __restrict__ A16,
    const _Float16* __restrict__ Wq16, const _Float16* __restrict__ Wk16,
    const _Float16* __restrict__ Wv16, const float2* __restrict__ rtab,
    _Float16* __restrict__ q16, _Float16* __restrict__ k16,
    _Float16* __restrict__ vT16) {
    __shared__ __align__(16) _Float16 As[128 * 128];   // 32 KB, swizzled
    __shared__ __align__(16) _Float16 Bs[64 * 128];    // 16 KB, swizzled
    const int tid = threadIdx.x;
    const int bx = blockIdx.x;
    const int m0 = blockIdx.y * 128;
    const int w = tid >> 6, lane = tid & 63;
    const int mm = lane & 15, quad = lane >> 4;

    const _Float16* bbase; int brb;
    if (bx < 12)      { bbase = Wq16; brb = bx * 64; }
    else if (bx < 15) { bbase = Wk16; brb = (bx - 12) * 64; }
    else              { bbase = Wv16; brb = (bx - 15) * 64; }

    const int rofs4 = lane >> 4;
    const int gs = lane & 15;

    const _Float16* agp[8]; lf16* alp[8];
    #pragma unroll
    for (int j = 0; j < 8; ++j) {
        int c = j * 4 + w;
        int rr = c * 4 + rofs4;
        int glog = gs ^ (rr & 15);
        agp[j] = A16 + (size_t)(m0 + rr) * KDIM + glog * 8;
        alp[j] = ((lf16*)As) + c * 512 + lane * 8;
    }
    const _Float16* bgp[4]; lf16* blp[4];
    #pragma unroll
    for (int j = 0; j < 4; ++j) {
        int c = j * 4 + w;
        int rr = c * 4 + rofs4;
        int glog = gs ^ (rr & 15);
        bgp[j] = bbase + (size_t)(brb + rr) * KDIM + glog * 8;
        blp[j] = ((lf16*)Bs) + c * 512 + lane * 8;
    }

    f32x4 acc[2][4] = {};

    for (int it = 0; it < 6; ++it) {
        const int ke = it * 128;
        __syncthreads();
        #pragma unroll
        for (int j = 0; j < 8; ++j) dma16(agp[j] + ke, alp[j]);
        #pragma unroll
        for (int j = 0; j < 4; ++j) dma16(bgp[j] + ke, blp[j]);
        __syncthreads();
        #pragma unroll
        for (int s = 0; s < 4; ++s) {
            const int gq = ((s * 4 + quad) ^ mm) * 8;
            f16x8 ah[2];
            #pragma unroll
            for (int mt = 0; mt < 2; ++mt)
                ah[mt] = *(const f16x8*)&As[(w * 32 + mt * 16 + mm) * 128 + gq];
            #pragma unroll
            for (int nt = 0; nt < 4; ++nt) {
                f16x8 bh = *(const f16x8*)&Bs[(nt * 16 + mm) * 128 + gq];
                #pragma unroll
                for (int mt = 0; mt < 2; ++mt)
                    acc[mt][nt] = MFMA16(ah[mt], bh, acc[mt][nt]);
            }
        }
    }

    // ---- fused epilogue (rotary + f16 emit) ----
    #pragma unroll
    for (int mt = 0; mt < 2; ++mt) {
        #pragma unroll
        for (int r = 0; r < 4; ++r) {
            int row = m0 + w * 32 + mt * 16 + quad * 4 + r;
            int t = row & (T_SEQ - 1);
            int b = row >> 11;
            if (bx < 12) {
                _Float16* dst = &q16[(size_t)row * E + bx * 64 + mm];
                #pragma unroll
                for (int nt = 0; nt < 2; ++nt) {
                    int d = nt * 16 + mm;
                    float2 cs = rtab[t * 32 + d];
                    float x1 = acc[mt][nt][r], x2 = acc[mt][nt + 2][r];
                    dst[nt * 16]       = (_Float16)((x1 * cs.x - x2 * cs.y) * SCALE);
                    dst[(nt + 2) * 16] = (_Float16)((x1 * cs.y + x2 * cs.x) * SCALE);
                }
            } else if (bx < 15) {
                int kvh = bx - 12;
                _Float16* dst = &k16[(((size_t)(b * 3 + kvh)) * T_SEQ + t) * 64 + mm];
                #pragma unroll
                for (int nt = 0; nt < 2; ++nt) {
                    int d = nt * 16 + mm;
                    float2 cs = rtab[t * 32 + d];
                    float x1 = acc[mt][nt][r], x2 = acc[mt][nt + 2][r];
                    dst[nt * 16]       = (_Float16)(x1 * cs.x - x2 * cs.y);
                    dst[(nt + 2) * 16] = (_Float16)(x1 * cs.y + x2 * cs.x);
                }
            } else {
                int kvh = bx - 15;
                #pragma unroll
                for (int nt = 0; nt < 4; ++nt) {
                    int d = nt * 16 + mm;
                    vT16[(((size_t)(b * 3 + kvh)) * 64 + d) * T_SEQ + t] = (_Float16)acc[mt][nt][r];
                }
            }
        }
    }
}

// ---------------- output-projection GEMM: 64x64 tile, BK=128 ----------------
__global__ __launch_bounds__(256) void gemm_out(
    const _Float16* __restrict__ A16, const _Float16* __restrict__ B16,
    float* __restrict__ C) {
    __shared__ __align__(16) _Float16 As[64 * 128];   // 16 KB
    __shared__ __align__(16) _Float16 Bs[64 * 128];   // 16 KB
    const int tid = threadIdx.x;
    const int n0 = blockIdx.x * 64;
    const int m0 = blockIdx.y * 64;
    const int w = tid >> 6, lane = tid & 63;
    const int mm = lane & 15, quad = lane >> 4;
    const int wm = (w & 1) * 32, wn = (w >> 1) * 32;

    const int rofs4 = lane >> 4;
    const int gs = lane & 15;

    const _Float16* agp[4]; lf16* alp[4];
    const _Float16* bgp[4]; lf16* blp[4];
    #pragma unroll
    for (int j = 0; j < 4; ++j) {
        int c = j * 4 + w;
        int rr = c * 4 + rofs4;
        int glog = gs ^ (rr & 15);
        agp[j] = A16 + (size_t)(m0 + rr) * KDIM + glog * 8;
        alp[j] = ((lf16*)As) + c * 512 + lane * 8;
        bgp[j] = B16 + (size_t)(n0 + rr) * KDIM + glog * 8;
        blp[j] = ((lf16*)Bs) + c * 512 + lane * 8;
    }

    f32x4 acc[2][2] = {};

    for (int it = 0; it < 6; ++it) {
        const int ke = it * 128;
        __syncthreads();
        #pragma unroll
        for (int j = 0; j < 4; ++j) dma16(agp[j] + ke, alp[j]);
        #pragma unroll
        for (int j = 0; j < 4; ++j) dma16(bgp[j] + ke, blp[j]);
        __syncthreads();
        #pragma unroll
        for (int s = 0; s < 4; ++s) {
            const int gq = ((s * 4 + quad) ^ mm) * 8;
            f16x8 ah[2], bh[2];
            #pragma unroll
            for (int mt = 0; mt < 2; ++mt)
                ah[mt] = *(const f16x8*)&As[(wm + mt * 16 + mm) * 128 + gq];
            #pragma unroll
            for (int nt = 0; nt < 2; ++nt)
                bh[nt] = *(const f16x8*)&Bs[(wn + nt * 16 + mm) * 128 + gq];
            #pragma unroll
            for (int nt = 0; nt < 2; ++nt)
                #pragma unroll
                for (int mt = 0; mt < 2; ++mt)
                    acc[mt][nt] = MFMA16(ah[mt], bh[nt], acc[mt][nt]);
        }
    }
    #pragma unroll
    for (int mt = 0; mt < 2; ++mt)
        #pragma unroll
        for (int r = 0; r < 4; ++r) {
            int row = m0 + wm + mt * 16 + quad * 4 + r;
            float* cp = &C[(size_t)row * 768 + n0 + wn + mm];
            #pragma unroll
            for (int nt = 0; nt < 2; ++nt)
                cp[nt * 16] = acc[mt][nt][r];
        }
}

// ---------------- MFMA flash attention v6: 128-key double-chunks ------------
// Block = (64 q, h, b). Waves: qh = w&1 (32 q-rows), kh = w>>1 (32-key half
// of each 64-key sub-chunk). One barrier pair per 128 keys (9 iters vs 17).
// k_s [128][64] swz(^row&7); vT_s [64][128] swz(^row&15); p_s per sub-chunk
// (wave-private, no barrier). Tail sub-chunk skipped wave-uniformly; staging
// overrun stays inside d_ws and is masked (exp(-inf)=0).
__global__ __launch_bounds__(256) void attn_mfma(const _Float16* __restrict__ q16,
                                                 const _Float16* __restrict__ k16,
                                                 const _Float16* __restrict__ vT16,
                                                 _Float16* __restrict__ aout16) {
    __shared__ __align__(16) char smem[16384 + 16384 + 10240];   // 42 KB
    _Float16* k_s  = (_Float16*)smem;                            // [128][64] swz
    _Float16* vT_s = (_Float16*)(smem + 16384);                  // [64][128] swz
    _Float16 (*p_s)[40] = (_Float16(*)[40])(smem + 32768);       // [128][40]
    float* ored = (float*)smem;                                  // [64][64] end overlay
    float* lred = (float*)(smem + 16384);                        // [64]     end overlay

    const int b = blockIdx.z, h = blockIdx.y;
    const int i0 = blockIdx.x * 64;
    const int plane = b * 3 + (h >> 2);
    const int tid = threadIdx.x;
    const int w = tid >> 6, lane = tid & 63;
    const int m = lane & 15, quad = lane >> 4;
    const int qh = w & 1, kh = w >> 1;
    const int xm = m & 7;

    int s0 = i0 - 512;      s0 = s0 < 0 ? 0 : (s0 > 1024 ? 1024 : s0);
    int sL = i0 + 63 - 512; sL = sL < 0 ? 0 : (sL > 1024 ? 1024 : sL);
    const int nc = (sL + WIN - s0 + 63) >> 6;          // 64-key sub-chunks
    const int ndc = (nc + 1) >> 1;                     // 128-key double-chunks

    int start_q[2];
    f16x8 qf[2][2];
    #pragma unroll
    for (int qt = 0; qt < 2; ++qt) {
        int qi = i0 + qh * 32 + qt * 16 + m;
        int sq = qi - 512; sq = sq < 0 ? 0 : (sq > 1024 ? 1024 : sq);
        start_q[qt] = sq;
        const _Float16* qp = &q16[((size_t)(b * T_SEQ + qi)) * E + h * 64 + quad * 8];
        qf[qt][0] = *(const f16x8*)&qp[0];
        qf[qt][1] = *(const f16x8*)&qp[32];
    }

    f32x4 o[2][4] = {};
    float l_run[2] = {0.0f, 0.0f};

    // K staging: 128 rows x 128B; seg = j*4+w covers rows seg*8+(lane>>3),
    // slot lane&7, logical granule slot^(row&7) = slot^(lane>>3).
    const int rofs8 = lane >> 3;
    const int glog8 = (lane & 7) ^ rofs8;
    const _Float16* kgb[4]; lf16* klw[4];
    #pragma unroll
    for (int j = 0; j < 4; ++j) {
        int rr = (j * 4 + w) * 8 + rofs8;
        kgb[j] = k16 + ((size_t)plane * T_SEQ + rr) * 64 + glog8 * 8;
        klw[j] = ((lf16*)k_s) + (j * 4 + w) * 512 + lane * 8;
    }
    // V staging: 64 rows x 256B; seg covers rows seg*4+(lane>>4), slot lane&15,
    // logical granule slot^(row&15).
    const int rofs4 = lane >> 4;
    const int gs = lane & 15;
    const _Float16* vgb[4]; lf16* vlw[4];
    #pragma unroll
    for (int j = 0; j < 4; ++j) {
        int rr = (j * 4 + w) * 4 + rofs4;
        int glog = gs ^ (rr & 15);
        vgb[j] = vT16 + ((size_t)plane * 64 + rr) * T_SEQ + glog * 8;
        vlw[j] = ((lf16*)vT_s) + (j * 4 + w) * 512 + lane * 8;
    }

    for (int ci = 0; ci < ndc; ++ci) {
        const int c0 = s0 + ci * 128;
        __syncthreads();
        #pragma unroll
        for (int j = 0; j < 4; ++j) dma16(kgb[j] + (size_t)c0 * 64, klw[j]);
        #pragma unroll
        for (int j = 0; j < 4; ++j) dma16(vgb[j] + c0, vlw[j]);
        __syncthreads();

        #pragma unroll
        for (int sc = 0; sc < 2; ++sc) {
            if (ci * 2 + sc >= nc) break;          // wave-uniform tail skip
            const int c0s = c0 + sc * 64;

            f32x4 st[2][2] = {};
            #pragma unroll
            for (int s = 0; s < 2; ++s) {
                #pragma unroll
                for (int kt = 0; kt < 2; ++kt) {
                    int row = sc * 64 + kh * 32 + kt * 16 + m;
                    int g = (s * 4 + quad) ^ xm;
                    f16x8 a = *(const f16x8*)&k_s[row * 64 + g * 8];
                    #pragma unroll
                    for (int qt = 0; qt < 2; ++qt)
                        st[kt][qt] = MFMA16(a, qf[qt][s], st[kt][qt]);
                }
            }

            const bool boundary = (c0s < sL) || (c0s + 63 > s0 + 1023);
            if (boundary) {
                #pragma unroll
                for (int kt = 0; kt < 2; ++kt)
                    #pragma unroll
                    for (int qt = 0; qt < 2; ++qt)
                        #pragma unroll
                        for (int r = 0; r < 4; ++r) {
                            int j = c0s + kh * 32 + kt * 16 + quad * 4 + r;
                            bool valid = (j >= start_q[qt]) && (j < start_q[qt] + WIN);
                            st[kt][qt][r] = valid ? st[kt][qt][r] : -INFINITY;
                        }
            }

            #pragma unroll
            for (int kt = 0; kt < 2; ++kt)
                #pragma unroll
                for (int qt = 0; qt < 2; ++qt) {
                    float p0 = __expf(st[kt][qt][0]);
                    float p1 = __expf(st[kt][qt][1]);
                    float p2 = __expf(st[kt][qt][2]);
                    float p3 = __expf(st[kt][qt][3]);
                    l_run[qt] += (p0 + p1) + (p2 + p3);
                    f16x4 pv = {(_Float16)p0, (_Float16)p1, (_Float16)p2, (_Float16)p3};
                    *(f16x4*)&p_s[w * 32 + qt * 16 + m][kt * 16 + quad * 4] = pv;
                }

            f16x8 bp[2];
            #pragma unroll
            for (int qt = 0; qt < 2; ++qt)
                bp[qt] = *(const f16x8*)&p_s[w * 32 + qt * 16 + m][quad * 8];
            #pragma unroll
            for (int mt = 0; mt < 4; ++mt) {
                int g = (sc * 8 + kh * 4 + quad) ^ m;
                f16x8 a = *(const f16x8*)&vT_s[(mt * 16 + m) * 128 + g * 8];
                #pragma unroll
                for (int qt = 0; qt < 2; ++qt)
                    o[qt][mt] = MFMA16(a, bp[qt], o[qt][mt]);
            }
        }
    }

    float l_tot[2];
    #pragma unroll
    for (int qt = 0; qt < 2; ++qt) {
        float l = l_run[qt];
        l += __shfl_xor(l, 16);
        l += __shfl_xor(l, 32);
        l_tot[qt] = l;
    }

    __syncthreads();
    if (kh == 1) {
        #pragma unroll
        for (int qt = 0; qt < 2; ++qt) {
            #pragma unroll
            for (int mt = 0; mt < 4; ++mt) {
                int idx = ((qh * 32 + qt * 16 + m) << 6) + mt * 16 + quad * 4;
                *(float4*)&ored[idx] = *(float4*)&o[qt][mt];
            }
            if (quad == 0) lred[qh * 32 + qt * 16 + m] = l_tot[qt];
        }
    }
    __syncthreads();
    if (kh == 0) {
        #pragma unroll
        for (int qt = 0; qt < 2; ++qt) {
            float rl = 1.0f / (l_tot[qt] + lred[qh * 32 + qt * 16 + m]);
            int qi = i0 + qh * 32 + qt * 16 + m;
            _Float16* op = &aout16[((size_t)(b * T_SEQ + qi)) * E + h * 64];
            #pragma unroll
            for (int mt = 0; mt < 4; ++mt) {
                int idx = ((qh * 32 + qt * 16 + m) << 6) + mt * 16 + quad * 4;
                float4 other = *(float4*)&ored[idx];
                #pragma unroll
                for (int r = 0; r < 4; ++r) {
                    float x = (o[qt][mt][r] + (&other.x)[r]) * rl;
                    op[mt * 16 + quad * 4 + r] = (_Float16)x;
                }
            }
        }
    }
}

extern "C" void kernel_launch(void* const* d_in, const int* in_sizes, int n_in,
                              void* d_out, int out_size, void* d_ws, size_t ws_size,
                              hipStream_t stream) {
    const float* hs = (const float*)d_in[0];
    const float* Wq = (const float*)d_in[1];
    const float* Wk = (const float*)d_in[2];
    const float* Wv = (const float*)d_in[3];
    const float* Wo = (const float*)d_in[4];
    float* out = (float*)d_out;

    _Float16* hs16   = (_Float16*)d_ws;             // 4096*768 f16
    _Float16* aout16 = hs16 + HS_SZ;                // 4096*768
    _Float16* q16    = aout16 + HS_SZ;              // 4096*768
    _Float16* k16    = q16 + HS_SZ;                 // 6*2048*64
    _Float16* vT16   = k16 + 6 * 2048 * 64;         // 6*64*2048
    _Float16* Wq16   = vT16 + 6 * 2048 * 64;        // 768*768
    _Float16* Wk16   = Wq16 + 768 * 768;            // 192*768
    _Float16* Wv16   = Wk16 + 192 * 768;            // 192*768
    _Float16* Wo16   = Wv16 + 192 * 768;            // 768*768
    float2*   rtab   = (float2*)(Wo16 + 768 * 768); // 2048*32 float2

    dim3 blk(256);
    prep<<<dim3((int)(HS_SZ / 8 / 256)), blk, 0, stream>>>(hs, Wq, Wk, Wv, Wo,
                                                           hs16, Wq16, Wk16, Wv16, Wo16, rtab);
    gemm_qkv<<<dim3(18, 32), blk, 0, stream>>>(hs16, Wq16, Wk16, Wv16, rtab, q16, k16, vT16);
    attn_mfma<<<dim3(32, 12, 2), blk, 0, stream>>>(q16, k16, vT16, aout16);
    gemm_out<<<dim3(12, 64), blk, 0, stream>>>(aout16, Wo16, out);
}

// Round 13
// 135.092 us; speedup vs baseline: 1.0529x; 1.0529x over previous
//
#include <hip/hip_runtime.h>
#include <math.h>

#define T_SEQ 2048
#define E 768
#define WIN 1024
#define KDIM 768
#define HS_SZ ((size_t)4096 * 768)
#define SCALE 0.21650635094610965f

typedef _Float16 f16x8 __attribute__((ext_vector_type(8)));
typedef _Float16 f16x4 __attribute__((ext_vector_type(4)));
typedef float f32x4 __attribute__((ext_vector_type(4)));
typedef __attribute__((address_space(3))) _Float16 lf16;

#define MFMA16(a, b, c) __builtin_amdgcn_mfma_f32_16x16x32_f16(a, b, c, 0, 0, 0)

__device__ __forceinline__ void dma16(const _Float16* g, lf16* l) {
    __builtin_amdgcn_global_load_lds(
        (const __attribute__((address_space(1))) void*)g,
        (__attribute__((address_space(3))) void*)l, 16, 0, 0);
}

// ---------------- prep: f16 casts + rotary table ----------------
__device__ __forceinline__ void cast8(const float* __restrict__ src,
                                      _Float16* __restrict__ dst, int i) {
    float4 a = *(const float4*)&src[i];
    float4 b = *(const float4*)&src[i + 4];
    f16x8 h;
    h[0] = (_Float16)a.x; h[1] = (_Float16)a.y; h[2] = (_Float16)a.z; h[3] = (_Float16)a.w;
    h[4] = (_Float16)b.x; h[5] = (_Float16)b.y; h[6] = (_Float16)b.z; h[7] = (_Float16)b.w;
    *(f16x8*)&dst[i] = h;
}

__global__ __launch_bounds__(256) void prep(
    const float* __restrict__ hs,
    const float* __restrict__ Wq, const float* __restrict__ Wk,
    const float* __restrict__ Wv, const float* __restrict__ Wo,
    _Float16* __restrict__ hs16,
    _Float16* __restrict__ Wq16, _Float16* __restrict__ Wk16,
    _Float16* __restrict__ Wv16, _Float16* __restrict__ Wo16,
    float2* __restrict__ rtab) {
    int tid = blockIdx.x * 256 + threadIdx.x;
    int i = tid * 8;
    if (i < 768 * 768) { cast8(Wq, Wq16, i); cast8(Wo, Wo16, i); }
    if (i < 192 * 768) { cast8(Wk, Wk16, i); cast8(Wv, Wv16, i); }
    cast8(hs, hs16, i);
    if (tid < 2048 * 32) {
        int t = tid >> 5, d = tid & 31;
        float inv = powf(10000.0f, -(float)(2 * d) * (1.0f / 64.0f));
        float s, c;
        sincosf((float)t * inv, &s, &c);
        rtab[tid] = make_float2(c, s);
    }
}

// ---------------- QKV GEMM: pure f16, 128x64, BK=128, DMA + XOR swizzle -----
__global__ __launch_bounds__(256) void gemm_qkv(
    const _Float16* __restrict__ A16,
    const _Float16* __restrict__ Wq16, const _Float16* __restrict__ Wk16,
    const _Float16* __restrict__ Wv16, const float2* __restrict__ rtab,
    _Float16* __restrict__ q16, _Float16* __restrict__ k16,
    _Float16* __restrict__ vT16) {
    __shared__ __align__(16) _Float16 As[128 * 128];   // 32 KB, swizzled
    __shared__ __align__(16) _Float16 Bs[64 * 128];    // 16 KB, swizzled
    const int tid = threadIdx.x;
    const int bx = blockIdx.x;
    const int m0 = blockIdx.y * 128;
    const int w = tid >> 6, lane = tid & 63;
    const int mm = lane & 15, quad = lane >> 4;

    const _Float16* bbase; int brb;
    if (bx < 12)      { bbase = Wq16; brb = bx * 64; }
    else if (bx < 15) { bbase = Wk16; brb = (bx - 12) * 64; }
    else              { bbase = Wv16; brb = (bx - 15) * 64; }

    const int rofs4 = lane >> 4;
    const int gs = lane & 15;

    const _Float16* agp[8]; lf16* alp[8];
    #pragma unroll
    for (int j = 0; j < 8; ++j) {
        int c = j * 4 + w;
        int rr = c * 4 + rofs4;
        int glog = gs ^ (rr & 15);
        agp[j] = A16 + (size_t)(m0 + rr) * KDIM + glog * 8;
        alp[j] = ((lf16*)As) + c * 512 + lane * 8;
    }
    const _Float16* bgp[4]; lf16* blp[4];
    #pragma unroll
    for (int j = 0; j < 4; ++j) {
        int c = j * 4 + w;
        int rr = c * 4 + rofs4;
        int glog = gs ^ (rr & 15);
        bgp[j] = bbase + (size_t)(brb + rr) * KDIM + glog * 8;
        blp[j] = ((lf16*)Bs) + c * 512 + lane * 8;
    }

    f32x4 acc[2][4] = {};

    for (int it = 0; it < 6; ++it) {
        const int ke = it * 128;
        __syncthreads();
        #pragma unroll
        for (int j = 0; j < 8; ++j) dma16(agp[j] + ke, alp[j]);
        #pragma unroll
        for (int j = 0; j < 4; ++j) dma16(bgp[j] + ke, blp[j]);
        __syncthreads();
        #pragma unroll
        for (int s = 0; s < 4; ++s) {
            const int gq = ((s * 4 + quad) ^ mm) * 8;
            f16x8 ah[2];
            #pragma unroll
            for (int mt = 0; mt < 2; ++mt)
                ah[mt] = *(const f16x8*)&As[(w * 32 + mt * 16 + mm) * 128 + gq];
            #pragma unroll
            for (int nt = 0; nt < 4; ++nt) {
                f16x8 bh = *(const f16x8*)&Bs[(nt * 16 + mm) * 128 + gq];
                #pragma unroll
                for (int mt = 0; mt < 2; ++mt)
                    acc[mt][nt] = MFMA16(ah[mt], bh, acc[mt][nt]);
            }
        }
    }

    // ---- fused epilogue (rotary + f16 emit) ----
    #pragma unroll
    for (int mt = 0; mt < 2; ++mt) {
        #pragma unroll
        for (int r = 0; r < 4; ++r) {
            int row = m0 + w * 32 + mt * 16 + quad * 4 + r;
            int t = row & (T_SEQ - 1);
            int b = row >> 11;
            if (bx < 12) {
                _Float16* dst = &q16[(size_t)row * E + bx * 64 + mm];
                #pragma unroll
                for (int nt = 0; nt < 2; ++nt) {
                    int d = nt * 16 + mm;
                    float2 cs = rtab[t * 32 + d];
                    float x1 = acc[mt][nt][r], x2 = acc[mt][nt + 2][r];
                    dst[nt * 16]       = (_Float16)((x1 * cs.x - x2 * cs.y) * SCALE);
                    dst[(nt + 2) * 16] = (_Float16)((x1 * cs.y + x2 * cs.x) * SCALE);
                }
            } else if (bx < 15) {
                int kvh = bx - 12;
                _Float16* dst = &k16[(((size_t)(b * 3 + kvh)) * T_SEQ + t) * 64 + mm];
                #pragma unroll
                for (int nt = 0; nt < 2; ++nt) {
                    int d = nt * 16 + mm;
                    float2 cs = rtab[t * 32 + d];
                    float x1 = acc[mt][nt][r], x2 = acc[mt][nt + 2][r];
                    dst[nt * 16]       = (_Float16)(x1 * cs.x - x2 * cs.y);
                    dst[(nt + 2) * 16] = (_Float16)(x1 * cs.y + x2 * cs.x);
                }
            } else {
                int kvh = bx - 15;
                #pragma unroll
                for (int nt = 0; nt < 4; ++nt) {
                    int d = nt * 16 + mm;
                    vT16[(((size_t)(b * 3 + kvh)) * 64 + d) * T_SEQ + t] = (_Float16)acc[mt][nt][r];
                }
            }
        }
    }
}

// ---------------- output-projection GEMM: 64x64 tile, BK=128 ----------------
__global__ __launch_bounds__(256) void gemm_out(
    const _Float16* __restrict__ A16, const _Float16* __restrict__ B16,
    float* __restrict__ C) {
    __shared__ __align__(16) _Float16 As[64 * 128];   // 16 KB
    __shared__ __align__(16) _Float16 Bs[64 * 128];   // 16 KB
    const int tid = threadIdx.x;
    const int n0 = blockIdx.x * 64;
    const int m0 = blockIdx.y * 64;
    const int w = tid >> 6, lane = tid & 63;
    const int mm = lane & 15, quad = lane >> 4;
    const int wm = (w & 1) * 32, wn = (w >> 1) * 32;

    const int rofs4 = lane >> 4;
    const int gs = lane & 15;

    const _Float16* agp[4]; lf16* alp[4];
    const _Float16* bgp[4]; lf16* blp[4];
    #pragma unroll
    for (int j = 0; j < 4; ++j) {
        int c = j * 4 + w;
        int rr = c * 4 + rofs4;
        int glog = gs ^ (rr & 15);
        agp[j] = A16 + (size_t)(m0 + rr) * KDIM + glog * 8;
        alp[j] = ((lf16*)As) + c * 512 + lane * 8;
        bgp[j] = B16 + (size_t)(n0 + rr) * KDIM + glog * 8;
        blp[j] = ((lf16*)Bs) + c * 512 + lane * 8;
    }

    f32x4 acc[2][2] = {};

    for (int it = 0; it < 6; ++it) {
        const int ke = it * 128;
        __syncthreads();
        #pragma unroll
        for (int j = 0; j < 4; ++j) dma16(agp[j] + ke, alp[j]);
        #pragma unroll
        for (int j = 0; j < 4; ++j) dma16(bgp[j] + ke, blp[j]);
        __syncthreads();
        #pragma unroll
        for (int s = 0; s < 4; ++s) {
            const int gq = ((s * 4 + quad) ^ mm) * 8;
            f16x8 ah[2], bh[2];
            #pragma unroll
            for (int mt = 0; mt < 2; ++mt)
                ah[mt] = *(const f16x8*)&As[(wm + mt * 16 + mm) * 128 + gq];
            #pragma unroll
            for (int nt = 0; nt < 2; ++nt)
                bh[nt] = *(const f16x8*)&Bs[(wn + nt * 16 + mm) * 128 + gq];
            #pragma unroll
            for (int nt = 0; nt < 2; ++nt)
                #pragma unroll
                for (int mt = 0; mt < 2; ++mt)
                    acc[mt][nt] = MFMA16(ah[mt], bh[nt], acc[mt][nt]);
        }
    }
    #pragma unroll
    for (int mt = 0; mt < 2; ++mt)
        #pragma unroll
        for (int r = 0; r < 4; ++r) {
            int row = m0 + wm + mt * 16 + quad * 4 + r;
            float* cp = &C[(size_t)row * 768 + n0 + wn + mm];
            #pragma unroll
            for (int nt = 0; nt < 2; ++nt)
                cp[nt * 16] = acc[mt][nt][r];
        }
}

// ---------------- MFMA flash attention v5: register-prefetch pipeline ------
// (R11 version — best measured. Block = (64 q, h, b); qh = w&1, kh = w>>1.)
__global__ __launch_bounds__(256) void attn_mfma(const _Float16* __restrict__ q16,
                                                 const _Float16* __restrict__ k16,
                                                 const _Float16* __restrict__ vT16,
                                                 _Float16* __restrict__ aout16) {
    __shared__ __align__(16) char smem[8192 + 8192 + 10240];   // 26.5 KB
    _Float16* k_s  = (_Float16*)smem;                          // [64][64] swz
    _Float16* vT_s = (_Float16*)(smem + 8192);                 // [64][64] swz
    _Float16 (*p_s)[40] = (_Float16(*)[40])(smem + 16384);     // [128][40]
    float* ored = (float*)smem;                                // [64][64] end overlay
    float* lred = (float*)(smem + 16384);                      // [64]     end overlay

    const int b = blockIdx.z, h = blockIdx.y;
    const int i0 = blockIdx.x * 64;
    const int plane = b * 3 + (h >> 2);
    const int tid = threadIdx.x;
    const int w = tid >> 6, lane = tid & 63;
    const int m = lane & 15, quad = lane >> 4;
    const int qh = w & 1, kh = w >> 1;
    const int xm = m & 7;

    int s0 = i0 - 512;      s0 = s0 < 0 ? 0 : (s0 > 1024 ? 1024 : s0);
    int sL = i0 + 63 - 512; sL = sL < 0 ? 0 : (sL > 1024 ? 1024 : sL);
    const int nc = (sL + WIN - s0 + 63) >> 6;

    int start_q[2];
    f16x8 qf[2][2];
    #pragma unroll
    for (int qt = 0; qt < 2; ++qt) {
        int qi = i0 + qh * 32 + qt * 16 + m;
        int sq = qi - 512; sq = sq < 0 ? 0 : (sq > 1024 ? 1024 : sq);
        start_q[qt] = sq;
        const _Float16* qp = &q16[((size_t)(b * T_SEQ + qi)) * E + h * 64 + quad * 8];
        qf[qt][0] = *(const f16x8*)&qp[0];
        qf[qt][1] = *(const f16x8*)&qp[32];
    }

    f32x4 o[2][4] = {};
    float l_run[2] = {0.0f, 0.0f};

    const int rofs = lane >> 3;
    const int glog = (lane & 7) ^ rofs;
    const _Float16* kgb[2]; const _Float16* vgb[2];
    _Float16* klw[2]; _Float16* vlw[2];
    #pragma unroll
    for (int j = 0; j < 2; ++j) {
        int rr = (j * 4 + w) * 8 + rofs;
        kgb[j] = k16 + ((size_t)plane * T_SEQ + rr) * 64 + glog * 8;
        vgb[j] = vT16 + ((size_t)plane * 64 + rr) * T_SEQ + glog * 8;
        klw[j] = k_s + (j * 4 + w) * 512 + lane * 8;
        vlw[j] = vT_s + (j * 4 + w) * 512 + lane * 8;
    }

    // prologue: load chunk 0 into regs
    f16x8 kr[2], vr[2];
    #pragma unroll
    for (int j = 0; j < 2; ++j) {
        kr[j] = *(const f16x8*)(kgb[j] + (size_t)s0 * 64);
        vr[j] = *(const f16x8*)(vgb[j] + s0);
    }

    for (int ci = 0; ci < nc; ++ci) {
        const int c0 = s0 + ci * 64;
        __syncthreads();                 // prev chunk's LDS consumers done
        #pragma unroll
        for (int j = 0; j < 2; ++j) {
            *(f16x8*)klw[j] = kr[j];
            *(f16x8*)vlw[j] = vr[j];
        }
        __syncthreads();                 // LDS ready
        if (ci + 1 < nc) {               // prefetch next chunk (hidden by compute)
            const int cn = c0 + 64;
            #pragma unroll
            for (int j = 0; j < 2; ++j) {
                kr[j] = *(const f16x8*)(kgb[j] + (size_t)cn * 64);
                vr[j] = *(const f16x8*)(vgb[j] + cn);
            }
        }

        f32x4 st[2][2] = {};
        #pragma unroll
        for (int s = 0; s < 2; ++s) {
            #pragma unroll
            for (int kt = 0; kt < 2; ++kt) {
                int row = kh * 32 + kt * 16 + m;
                int g = (s * 4 + quad) ^ xm;
                f16x8 a = *(const f16x8*)&k_s[row * 64 + g * 8];
                #pragma unroll
                for (int qt = 0; qt < 2; ++qt)
                    st[kt][qt] = MFMA16(a, qf[qt][s], st[kt][qt]);
            }
        }

        const bool boundary = (c0 < sL) || (c0 + 63 > s0 + 1023);
        if (boundary) {
            #pragma unroll
            for (int kt = 0; kt < 2; ++kt)
                #pragma unroll
                for (int qt = 0; qt < 2; ++qt)
                    #pragma unroll
                    for (int r = 0; r < 4; ++r) {
                        int j = c0 + kh * 32 + kt * 16 + quad * 4 + r;
                        bool valid = (j >= start_q[qt]) && (j < start_q[qt] + WIN);
                        st[kt][qt][r] = valid ? st[kt][qt][r] : -INFINITY;
                    }
        }

        #pragma unroll
        for (int kt = 0; kt < 2; ++kt)
            #pragma unroll
            for (int qt = 0; qt < 2; ++qt) {
                float p0 = __expf(st[kt][qt][0]);
                float p1 = __expf(st[kt][qt][1]);
                float p2 = __expf(st[kt][qt][2]);
                float p3 = __expf(st[kt][qt][3]);
                l_run[qt] += (p0 + p1) + (p2 + p3);
                f16x4 pv = {(_Float16)p0, (_Float16)p1, (_Float16)p2, (_Float16)p3};
                *(f16x4*)&p_s[w * 32 + qt * 16 + m][kt * 16 + quad * 4] = pv;
            }

        f16x8 bp[2];
        #pragma unroll
        for (int qt = 0; qt < 2; ++qt)
            bp[qt] = *(const f16x8*)&p_s[w * 32 + qt * 16 + m][quad * 8];
        #pragma unroll
        for (int mt = 0; mt < 4; ++mt) {
            int g = (kh * 4 + quad) ^ xm;
            f16x8 a = *(const f16x8*)&vT_s[(mt * 16 + m) * 64 + g * 8];
            #pragma unroll
            for (int qt = 0; qt < 2; ++qt)
                o[qt][mt] = MFMA16(a, bp[qt], o[qt][mt]);
        }
    }

    float l_tot[2];
    #pragma unroll
    for (int qt = 0; qt < 2; ++qt) {
        float l = l_run[qt];
        l += __shfl_xor(l, 16);
        l += __shfl_xor(l, 32);
        l_tot[qt] = l;
    }

    __syncthreads();
    if (kh == 1) {
        #pragma unroll
        for (int qt = 0; qt < 2; ++qt) {
            #pragma unroll
            for (int mt = 0; mt < 4; ++mt) {
                int idx = ((qh * 32 + qt * 16 + m) << 6) + mt * 16 + quad * 4;
                *(float4*)&ored[idx] = *(float4*)&o[qt][mt];
            }
            if (quad == 0) lred[qh * 32 + qt * 16 + m] = l_tot[qt];
        }
    }
    __syncthreads();
    if (kh == 0) {
        #pragma unroll
        for (int qt = 0; qt < 2; ++qt) {
            float rl = 1.0f / (l_tot[qt] + lred[qh * 32 + qt * 16 + m]);
            int qi = i0 + qh * 32 + qt * 16 + m;
            _Float16* op = &aout16[((size_t)(b * T_SEQ + qi)) * E + h * 64];
            #pragma unroll
            for (int mt = 0; mt < 4; ++mt) {
                int idx = ((qh * 32 + qt * 16 + m) << 6) + mt * 16 + quad * 4;
                float4 other = *(float4*)&ored[idx];
                #pragma unroll
                for (int r = 0; r < 4; ++r) {
                    float x = (o[qt][mt][r] + (&other.x)[r]) * rl;
                    op[mt * 16 + quad * 4 + r] = (_Float16)x;
                }
            }
        }
    }
}

extern "C" void kernel_launch(void* const* d_in, const int* in_sizes, int n_in,
                              void* d_out, int out_size, void* d_ws, size_t ws_size,
                              hipStream_t stream) {
    const float* hs = (const float*)d_in[0];
    const float* Wq = (const float*)d_in[1];
    const float* Wk = (const float*)d_in[2];
    const float* Wv = (const float*)d_in[3];
    const float* Wo = (const float*)d_in[4];
    float* out = (float*)d_out;

    _Float16* hs16   = (_Float16*)d_ws;             // 4096*768 f16
    _Float16* aout16 = hs16 + HS_SZ;                // 4096*768
    _Float16* q16    = aout16 + HS_SZ;              // 4096*768
    _Float16* k16    = q16 + HS_SZ;                 // 6*2048*64
    _Float16* vT16   = k16 + 6 * 2048 * 64;         // 6*64*2048
    _Float16* Wq16   = vT16 + 6 * 2048 * 64;        // 768*768
    _Float16* Wk16   = Wq16 + 768 * 768;            // 192*768
    _Float16* Wv16   = Wk16 + 192 * 768;            // 192*768
    _Float16* Wo16   = Wv16 + 192 * 768;            // 768*768
    float2*   rtab   = (float2*)(Wo16 + 768 * 768); // 2048*32 float2

    dim3 blk(256);
    prep<<<dim3((int)(HS_SZ / 8 / 256)), blk, 0, stream>>>(hs, Wq, Wk, Wv, Wo,
                                                           hs16, Wq16, Wk16, Wv16, Wo16, rtab);
    gemm_qkv<<<dim3(18, 32), blk, 0, stream>>>(hs16, Wq16, Wk16, Wv16, rtab, q16, k16, vT16);
    attn_mfma<<<dim3(32, 12, 2), blk, 0, stream>>>(q16, k16, vT16, aout16);
    gemm_out<<<dim3(12, 64), blk, 0, stream>>>(aout16, Wo16, out);
}